// Round 7
// baseline (389.803 us; speedup 1.0000x reference)
//
#include <hip/hip_runtime.h>

typedef __attribute__((ext_vector_type(4))) float f32x4;
typedef __attribute__((ext_vector_type(8))) short s16x8;

#define IN_F 512
#define OUT_F 512
#define STYLE_F 256

typedef __attribute__((address_space(1))) const void gvoid;
typedef __attribute__((address_space(3))) void svoid;

__device__ __forceinline__ unsigned short f2bf(float f) {
    unsigned int u = __builtin_bit_cast(unsigned int, f);
    u += 0x7FFFu + ((u >> 16) & 1u);   // round-to-nearest-even
    return (unsigned short)(u >> 16);
}

// pack 8 fp32 -> 8 bf16 (RNE) via v_cvt_pk_bf16_f32
__device__ __forceinline__ s16x8 cvt8(f32x4 a, f32x4 b) {
    union { unsigned int w[4]; s16x8 v; } u;
    asm("v_cvt_pk_bf16_f32 %0, %1, %2" : "=v"(u.w[0]) : "v"(a[0]), "v"(a[1]));
    asm("v_cvt_pk_bf16_f32 %0, %1, %2" : "=v"(u.w[1]) : "v"(a[2]), "v"(a[3]));
    asm("v_cvt_pk_bf16_f32 %0, %1, %2" : "=v"(u.w[2]) : "v"(b[0]), "v"(b[1]));
    asm("v_cvt_pk_bf16_f32 %0, %1, %2" : "=v"(u.w[3]) : "v"(b[2]), "v"(b[3]));
    return u.v;
}

// ---------------- prep1: alpha/beta GEMVs (2048 dots of length 256) --------
__global__ __launch_bounds__(256) void prep1_kernel(
    const float* __restrict__ z,
    const float* __restrict__ w_alpha,
    const float* __restrict__ b_alpha,
    const float* __restrict__ w_beta,
    const float* __restrict__ b_beta,
    float* __restrict__ alpha,
    float* __restrict__ beta)
{
    int gid = blockIdx.x * 256 + threadIdx.x;
    if (gid >= 2048) return;
    int t = gid & 1023;
    int b = t >> 9;
    int i = t & 511;
    const float* zr = z + b * STYLE_F;
    const float* wr = (gid < 1024 ? w_alpha : w_beta) + i * STYLE_F;
    float acc = 0.f;
    #pragma unroll 4
    for (int kk = 0; kk < STYLE_F; kk += 4) {
        float4 zv = *reinterpret_cast<const float4*>(zr + kk);
        float4 vv = *reinterpret_cast<const float4*>(wr + kk);
        acc += zv.x * vv.x + zv.y * vv.y + zv.z * vv.z + zv.w * vv.w;
    }
    if (gid < 1024) alpha[t] = acc + b_alpha[i];
    else            beta[t]  = acc + b_beta[i];
}

// ---------------- prep2: W * alpha_b -> bf16 fragment order, per batch -----
// wfragB[b] element index = (((ks*32 + nf)*64 + lane)*8 + e)
//   holds weight[n = nf*16 + (lane&15)][k = ks*32 + (lane>>4)*8 + e] * alpha[b][k]
__global__ __launch_bounds__(256) void prep2_kernel(
    const float* __restrict__ weight,
    const float* __restrict__ alpha,
    unsigned short* __restrict__ wfragB)
{
    int gid = blockIdx.x * 256 + threadIdx.x;   // 131072 threads total
    int b = gid >> 16;                          // 65536 threads per batch
    int f = (gid & 65535) << 2;
    int e0 = f & 7;                 // 0 or 4
    int l  = (f >> 3) & 63;
    int nf = (f >> 9) & 31;
    int ks = f >> 14;               // 0..15
    int n  = nf * 16 + (l & 15);
    int k  = ks * 32 + ((l >> 4) << 3) + e0;
    float4 wv = *reinterpret_cast<const float4*>(weight + n * IN_F + k);
    float4 av = *reinterpret_cast<const float4*>(alpha + b * IN_F + k);
    ushort4 o;
    o.x = f2bf(wv.x * av.x); o.y = f2bf(wv.y * av.y);
    o.z = f2bf(wv.z * av.z); o.w = f2bf(wv.w * av.w);
    *reinterpret_cast<ushort4*>(wfragB + b * 262144 + f) = o;
}

// ---------------- main GEMM: out = x_bf16 @ (W*alpha_b)^T + beta -----------
// Persistent: 256 blocks (1/CU), 8 tiles of BM=128 each, BN=512, BK=64.
// 512 thr = 8 waves (2M x 4N), wave tile 64x128, acc[4][8].
// Per step: issue {B-slice0(8), B-slice1(8), DMA-next(4)}; waits
// vmcnt(12)/vmcnt(4)/vmcnt(0) -- DMA in flight the whole step, drained
// just before the next barrier (per-wave-own-DMA-then-barrier invariant).
__global__ __launch_bounds__(512, 2) void modlin_kernel(
    const float* __restrict__ x,
    const unsigned short* __restrict__ wfragB,
    const float* __restrict__ beta,
    float* __restrict__ out)
{
    // A-tile buf: 128 rows x 64 k fp32. Row r = 256 B = 16 units of 16 B.
    // unit u stored at slot = (u&8) | ((u&7)^(r&7)); byte = buf*32768+r*256+slot*16
    __shared__ __align__(16) char lds[2 * 32768];

    const int tid = threadIdx.x;
    const int blk = blockIdx.x;              // 256 blocks, 8 tiles each
    const int b   = blk >> 7;                // batch index (0/1)

    const int l  = tid & 63;
    const int w  = tid >> 6;                 // wave 0..7
    const int wm = w >> 2;                   // 0..1 (M)
    const int wn = w & 3;                    // 0..3 (N)
    const int fr = l & 15;
    const int fq = l >> 4;                   // 0..3
    const int wvbase = w << 10;              // 1 KiB per wave per DMA instr

    // ---- DMA source map: instr i writes LDS unit U=i*512+tid -> row i*32+dr,
    //      slot tid&15; source column pre-swizzled so LDS stays linear.
    const int dr = tid >> 4;                 // row-in-32-group
    const int du = (tid & 8) | ((tid & 7) ^ (dr & 7));   // pre-swizzled unit
    const float* xp0 = x + (size_t)(blk * 1024 +  0 + dr) * IN_F + du * 4;
    const float* xp1 = x + (size_t)(blk * 1024 + 32 + dr) * IN_F + du * 4;
    const float* xp2 = x + (size_t)(blk * 1024 + 64 + dr) * IN_F + du * 4;
    const float* xp3 = x + (size_t)(blk * 1024 + 96 + dr) * IN_F + du * 4;

    // ---- ds_read byte addrs per (mf, half); +S*128 selects k-slice (bit-3 of
    //      slot is additive under the XOR-over-low-3-bits swizzle)
    int va[8];
    #pragma unroll
    for (int mf = 0; mf < 4; ++mf) {
        int R = wm * 64 + mf * 16 + fr;
        va[mf * 2 + 0] = R * 256 + ((((fq * 2) + 0) ^ (fr & 7)) << 4);
        va[mf * 2 + 1] = R * 256 + ((((fq * 2) + 1) ^ (fr & 7)) << 4);
    }

    // ---- B addressing (L2-resident)
    const char* bbp = (const char*)wfragB + (size_t)b * 524288;
    const unsigned vobase = (unsigned)(wn * 8192 + l * 16);

    // ---- beta preload
    float bv[8];
    #pragma unroll
    for (int nf = 0; nf < 8; ++nf)
        bv[nf] = beta[b * OUT_F + wn * 128 + nf * 16 + fr];

    f32x4 acc[4][8];
    s16x8 bb[8], bc[8];

    #define ISSUE4(NB)                                                         \
        do {                                                                   \
            __builtin_amdgcn_global_load_lds((gvoid*)xp0,                      \
                (svoid*)(lds + (NB) * 32768 + wvbase +     0), 16, 0, 0);      \
            __builtin_amdgcn_global_load_lds((gvoid*)xp1,                      \
                (svoid*)(lds + (NB) * 32768 + wvbase +  8192), 16, 0, 0);      \
            __builtin_amdgcn_global_load_lds((gvoid*)xp2,                      \
                (svoid*)(lds + (NB) * 32768 + wvbase + 16384), 16, 0, 0);      \
            __builtin_amdgcn_global_load_lds((gvoid*)xp3,                      \
                (svoid*)(lds + (NB) * 32768 + wvbase + 24576), 16, 0, 0);      \
        } while (0)

    #define LOADB8(dst, KS)                                                    \
        do {                                                                   \
            unsigned voA_ = vobase + (unsigned)(KS) * 32768u;                  \
            unsigned voB_ = voA_ + 4096u;                                      \
            _Pragma("unroll")                                                  \
            for (int nf_ = 0; nf_ < 4; ++nf_) {                                \
                asm volatile("global_load_dwordx4 %0, %1, %2 offset:%3"        \
                    : "=v"(dst[nf_])     : "v"(voA_), "s"(bbp),                \
                      "n"(nf_ * 1024) : "memory");                             \
                asm volatile("global_load_dwordx4 %0, %1, %2 offset:%3"        \
                    : "=v"(dst[nf_ + 4]) : "v"(voB_), "s"(bbp),                \
                      "n"(nf_ * 1024) : "memory");                             \
            }                                                                  \
        } while (0)

    #define READA(dst, BUF, S)                                                 \
        do {                                                                   \
            _Pragma("unroll")                                                  \
            for (int mf_ = 0; mf_ < 4; ++mf_) {                                \
                f32x4 r0_ = *(const f32x4*)(lds + (BUF) * 32768 + (S) * 128    \
                                            + va[mf_ * 2 + 0]);                \
                f32x4 r1_ = *(const f32x4*)(lds + (BUF) * 32768 + (S) * 128    \
                                            + va[mf_ * 2 + 1]);                \
                dst[mf_] = cvt8(r0_, r1_);                                     \
            }                                                                  \
        } while (0)

    #define MFMA32(A4, B8)                                                     \
        do {                                                                   \
            _Pragma("unroll")                                                  \
            for (int nf_ = 0; nf_ < 8; ++nf_)                                  \
                _Pragma("unroll")                                              \
                for (int mf_ = 0; mf_ < 4; ++mf_)                              \
                    acc[mf_][nf_] = __builtin_amdgcn_mfma_f32_16x16x32_bf16(   \
                        A4[mf_], B8[nf_], acc[mf_][nf_], 0, 0, 0);             \
        } while (0)

    // ---- prologue: DMA(tile0,step0) into buf0, drain own DMA
    ISSUE4(0);
    xp0 += 64; xp1 += 64; xp2 += 64; xp3 += 64;
    asm volatile("s_waitcnt vmcnt(0)" ::: "memory");
    __builtin_amdgcn_sched_barrier(0);

    for (int j = 0; j < 8; ++j) {
        #pragma unroll
        for (int mf = 0; mf < 4; ++mf)
            #pragma unroll
            for (int nf = 0; nf < 8; ++nf)
                acc[mf][nf] = (f32x4){0.f, 0.f, 0.f, 0.f};

        #pragma unroll
        for (int t = 0; t < 8; ++t) {
            const int buf  = t & 1;
            const int nbuf = buf ^ 1;
            __builtin_amdgcn_s_barrier();
            __builtin_amdgcn_sched_barrier(0);

            // issue order: B slice0 (oldest), B slice1, then next-step DMA
            LOADB8(bb, t * 2);
            LOADB8(bc, t * 2 + 1);
            const bool last = (t == 7) && (j == 7);
            if (t < 7) {
                ISSUE4(nbuf);
                xp0 += 64; xp1 += 64; xp2 += 64; xp3 += 64;
            } else if (j < 7) {
                // tile boundary: pre-advance to next tile's k=0 BEFORE issue
                xp0 += 65024; xp1 += 65024; xp2 += 65024; xp3 += 65024;
                ISSUE4(nbuf);
                xp0 += 64; xp1 += 64; xp2 += 64; xp3 += 64;
            }

            s16x8 a0[4];
            READA(a0, buf, 0);
            if (!last) asm volatile("s_waitcnt vmcnt(12)" ::: "memory");
            else       asm volatile("s_waitcnt vmcnt(8)"  ::: "memory");
            __builtin_amdgcn_sched_barrier(0);
            MFMA32(a0, bb);

            s16x8 a1[4];
            READA(a1, buf, 1);
            if (!last) asm volatile("s_waitcnt vmcnt(4)" ::: "memory");
            else       asm volatile("s_waitcnt vmcnt(0)" ::: "memory");
            __builtin_amdgcn_sched_barrier(0);
            MFMA32(a1, bc);

            if (!last) {
                // drain own DMA before the next barrier (buffer handoff)
                asm volatile("s_waitcnt vmcnt(0)" ::: "memory");
                __builtin_amdgcn_sched_barrier(0);
            }
        }

        // ---- tile epilogue: add beta, store fp32 (overlaps next tile's steps)
        float* op = out + (size_t)(blk * 1024 + j * 128 + wm * 64 + fq * 4) * OUT_F
                        + wn * 128 + fr;
        #pragma unroll
        for (int nf = 0; nf < 8; ++nf)
            #pragma unroll
            for (int mf = 0; mf < 4; ++mf) {
                float* p = op + (mf * 16) * OUT_F + nf * 16;
                p[0 * OUT_F] = acc[mf][nf][0] + bv[nf];
                p[1 * OUT_F] = acc[mf][nf][1] + bv[nf];
                p[2 * OUT_F] = acc[mf][nf][2] + bv[nf];
                p[3 * OUT_F] = acc[mf][nf][3] + bv[nf];
            }
    }

    #undef ISSUE4
    #undef LOADB8
    #undef READA
    #undef MFMA32
}

extern "C" void kernel_launch(void* const* d_in, const int* in_sizes, int n_in,
                              void* d_out, int out_size, void* d_ws, size_t ws_size,
                              hipStream_t stream)
{
    const float* x       = (const float*)d_in[0];
    const float* z       = (const float*)d_in[1];
    const float* weight  = (const float*)d_in[2];
    const float* w_alpha = (const float*)d_in[3];
    const float* b_alpha = (const float*)d_in[4];
    const float* w_beta  = (const float*)d_in[5];
    const float* b_beta  = (const float*)d_in[6];
    float* out = (float*)d_out;

    unsigned short* wfragB = (unsigned short*)d_ws;          // 2 x 512 KiB
    float* alpha = (float*)((char*)d_ws + 1048576);          // 4 KiB
    float* beta  = alpha + 2 * IN_F;                         // 4 KiB

    prep1_kernel<<<8, 256, 0, stream>>>(z, w_alpha, b_alpha, w_beta, b_beta,
                                        alpha, beta);
    prep2_kernel<<<512, 256, 0, stream>>>(weight, alpha, wfragB);
    modlin_kernel<<<256, 512, 0, stream>>>(x, wfragB, beta, out);
}